// Round 2
// baseline (456.442 us; speedup 1.0000x reference)
//
#include <hip/hip_runtime.h>

// Sinkhorn-Knopp on B independent 8x8 fp32 matrices.
//
// Round-1 lesson: one-matrix-per-thread with direct global access gives each
// vmem instruction a 256-B lane stride -> 64 cache lines per instruction
// (8x amplification of TA/TCP transactions) -> 1.2 TB/s. Fix: coalesced
// global <-> LDS staging with an XOR swizzle, compute stays one matrix per
// thread entirely in VGPRs.

#define N 8
#define TPB 256   // threads per block == matrices per block; 16 float4/matrix

__global__ __launch_bounds__(TPB) void sinkhorn8_kernel(
    const float* __restrict__ x,
    float* __restrict__ out,
    const int* __restrict__ num_iters_p,
    int nF4)   // total float4 count = B*16
{
    // 256 matrices * 16 float4 = 64 KiB. slot = m*16 + (k ^ (m & 15)):
    // both the coalesced access (m varies across lanes) and the per-thread
    // matrix access (k varies per instruction) hit all 32 banks evenly.
    __shared__ float4 lds[TPB * 16];

    const int t = threadIdx.x;
    const size_t blockBase = (size_t)blockIdx.x * (TPB * 16);  // in float4s
    const int num_iters = *num_iters_p;

    const float4* __restrict__ xv = (const float4*)x;
    float4* __restrict__ ov = (float4*)out;

    // ---- Stage in: coalesced global -> swizzled LDS ----
#pragma unroll
    for (int k = 0; k < 16; ++k) {
        size_t f = blockBase + t + k * TPB;
        if (f < (size_t)nF4) {
            float4 v = xv[f];
            int fl = t + k * TPB;       // float4 index within block tile
            int m  = fl >> 4;           // matrix within block
            int k4 = fl & 15;
            lds[(m << 4) | (k4 ^ (m & 15))] = v;
        }
    }
    __syncthreads();

    // ---- Each thread pulls its own matrix, computes in registers ----
    float M[N * N];
#pragma unroll
    for (int k = 0; k < 16; ++k) {
        float4 v = lds[(t << 4) | (k ^ (t & 15))];
        M[4 * k + 0] = __expf(v.x);
        M[4 * k + 1] = __expf(v.y);
        M[4 * k + 2] = __expf(v.z);
        M[4 * k + 3] = __expf(v.w);
    }

    for (int it = 0; it < num_iters; ++it) {
        // Row normalize
#pragma unroll
        for (int r = 0; r < N; ++r) {
            float s = 0.f;
#pragma unroll
            for (int c = 0; c < N; ++c) s += M[r * N + c];
            float inv = __builtin_amdgcn_rcpf(s);
#pragma unroll
            for (int c = 0; c < N; ++c) M[r * N + c] *= inv;
        }
        // Col normalize
#pragma unroll
        for (int c = 0; c < N; ++c) {
            float s = 0.f;
#pragma unroll
            for (int r = 0; r < N; ++r) s += M[r * N + c];
            float inv = __builtin_amdgcn_rcpf(s);
#pragma unroll
            for (int r = 0; r < N; ++r) M[r * N + c] *= inv;
        }
    }

    // ---- Stage out: registers -> swizzled LDS ----
    // (thread t only touches matrix-t slots, which only thread t read above,
    //  so no barrier needed before these writes)
#pragma unroll
    for (int k = 0; k < 16; ++k) {
        float4 v;
        v.x = M[4 * k + 0];
        v.y = M[4 * k + 1];
        v.z = M[4 * k + 2];
        v.w = M[4 * k + 3];
        lds[(t << 4) | (k ^ (t & 15))] = v;
    }
    __syncthreads();

    // ---- Coalesced LDS -> global ----
#pragma unroll
    for (int k = 0; k < 16; ++k) {
        size_t f = blockBase + t + k * TPB;
        if (f < (size_t)nF4) {
            int fl = t + k * TPB;
            int m  = fl >> 4;
            int k4 = fl & 15;
            ov[f] = lds[(m << 4) | (k4 ^ (m & 15))];
        }
    }
}

extern "C" void kernel_launch(void* const* d_in, const int* in_sizes, int n_in,
                              void* d_out, int out_size, void* d_ws, size_t ws_size,
                              hipStream_t stream) {
    const float* x = (const float*)d_in[0];
    const int* num_iters = (const int*)d_in[1];
    float* out = (float*)d_out;

    int nF4 = in_sizes[0] / 4;                 // total float4s
    int B = in_sizes[0] / (N * N);             // 1048576 matrices
    int grid = (B + TPB - 1) / TPB;            // 4096 blocks

    sinkhorn8_kernel<<<grid, TPB, 0, stream>>>(x, out, num_iters, nF4);
}